// Round 12
// baseline (222.351 us; speedup 1.0000x reference)
//
#include <hip/hip_runtime.h>
#include <hip/hip_bf16.h>
#include <stdint.h>

#define NNODE   17
#define FDIM    64
#define NBLOCK  768
#define TOTW    (NBLOCK*4)       // 3072 waves, graph-stride
#define NGRAPH  65536
#define GBYTES  4352             // 17*64*4 bytes per graph
#define GFLOAT  1088
#define WSTR    136              // W2T row stride in u16 (272B = 17*16 -> b128-aligned)

typedef __attribute__((ext_vector_type(8)))  short short8v;
typedef __attribute__((ext_vector_type(4)))  float f32x4;
typedef __attribute__((ext_vector_type(16))) float f32x16;
typedef __attribute__((ext_vector_type(2)))  unsigned int uint2v;

__device__ __forceinline__ uint32_t bf16b(float f) {
    uint32_t u = __float_as_uint(f);
    return (u + 0x7fffu + ((u >> 16) & 1u)) >> 16;   // RNE (prologue only)
}
__device__ __forceinline__ uint32_t cvtpk(float lo, float hi) {   // v_cvt_pk_bf16_f32
    __hip_bfloat162 b = __float22bfloat162_rn(make_float2(lo, hi));
    return *reinterpret_cast<uint32_t*>(&b);
}
__device__ __forceinline__ short8v mk8(uint32_t w0, uint32_t w1, uint32_t w2, uint32_t w3) {
    union { uint32_t u[4]; short8v v; } c;
    c.u[0] = w0; c.u[1] = w1; c.u[2] = w2; c.u[3] = w3;
    return c.v;
}
__device__ __forceinline__ void dma16(const void* g, void* l) {   // global_load_lds_dwordx4
    __builtin_amdgcn_global_load_lds((const __attribute__((address_space(1))) uint32_t*)g,
                                     (__attribute__((address_space(3))) uint32_t*)l, 16, 0, 0);
}

// Per-wave DMA-staged strips, barrier-free steady state, graph-stride grid.
__global__ __launch_bounds__(256, 3) void egc_kernel(
    const float* __restrict__ x, const float* __restrict__ adj,
    const float* __restrict__ wself, const float* __restrict__ wneigh,
    const float* __restrict__ bias, float* __restrict__ out)
{
    __shared__ __align__(16) float    sStrip[4][GFLOAT];     // 17408 B (per-wave strips)
    __shared__ __align__(16) uint16_t sW[64 * WSTR];         // 17408 B (W2T, static)
    __shared__ float sAdj[NNODE * NNODE];
    __shared__ float sBias[FDIM];

    const int t  = threadIdx.x;
    const int l  = t & 63;
    const int wv = t >> 6;
    const int n_ = l & 31;       // A.m / B.n / D.col
    const int h_ = l >> 5;       // k-half / D-row +4

    // ---- per-lane loop-invariant swizzled offsets ----------------------------
    // Strip layout: stored[r*256+o] = x[r*256 + (o ^ ((r&7)<<4))]  (swz within 128B line)
    int srcB[5];                 // DMA source byte offsets (lds linear dest j*1024+l*16)
    #pragma unroll
    for (int j = 0; j < 5; ++j) {
        int b0 = j * 1024 + l * 16;
        int r = b0 >> 8, o = b0 & 255;
        srcB[j] = r * 256 + (o ^ ((r & 7) << 4));
    }
    const int rr = (n_ < 16) ? n_ : 16;          // clamped row (lanes 17..31 -> finite dup)
    const int sw = (rr & 7) << 4;
    int rd0 = rr*256 + ((  0 + 32*h_      ) ^ sw), rd1 = rr*256 + ((  0 + 32*h_ + 16) ^ sw);
    int rd2 = rr*256 + (( 64 + 32*h_      ) ^ sw), rd3 = rr*256 + (( 64 + 32*h_ + 16) ^ sw);
    int rd4 = rr*256 + ((128 + 32*h_      ) ^ sw), rd5 = rr*256 + ((128 + 32*h_ + 16) ^ sw);
    int rd6 = rr*256 + ((192 + 32*h_      ) ^ sw), rd7 = rr*256 + ((192 + 32*h_ + 16) ^ sw);

    char* sb = (char*)&sStrip[wv][0];
    int g = blockIdx.x * 4 + wv;                 // first graph for this wave

    // issue DMA for graph 0 immediately (completes under the prologue)
    {
        const char* gb = (const char*)x + (size_t)g * GBYTES;
        #pragma unroll
        for (int j = 0; j < 4; ++j) dma16(gb + srcB[j], sb + j * 1024);
        if (l < 16) dma16(gb + srcB[4], sb + 4096);
    }

    // ---- prologue: stage W2T[o][k] (k<64: Ws[k][o] else Wn[k-64][o]) ---------
    for (int idx = t; idx < FDIM * 128; idx += 256) {
        int o = idx >> 7, k = idx & 127;
        float v = (k < 64) ? wself[k * 64 + o] : wneigh[(k - 64) * 64 + o];
        sW[o * WSTR + k] = (uint16_t)bf16b(v);
    }
    for (int i = t; i < NNODE * NNODE; i += 256) sAdj[i] = adj[i];
    if (t < FDIM) sBias[t] = bias[t];
    __syncthreads();

    // W B-frags: B[k=16ks+8h_+e][n=32hf+n_]  (b128 reads, 16B-aligned via WSTR=136)
    short8v wS[2][4], wN[2][4];
    #pragma unroll
    for (int hf = 0; hf < 2; ++hf)
        #pragma unroll
        for (int ks = 0; ks < 4; ++ks) {
            wS[hf][ks] = *(const short8v*)&sW[(32*hf + n_) * WSTR + 16*ks + 8*h_];
            wN[hf][ks] = *(const short8v*)&sW[(32*hf + n_) * WSTR + 64 + 16*ks + 8*h_];
        }
    const float bias0 = sBias[n_], bias1 = sBias[32 + n_];

    // adj A-frags: A[m=n_][k=16ks+8h_+e] = adj[n_][k], explicit zero pad (no NaN)
    short8v adjA[2];
    #pragma unroll
    for (int ks = 0; ks < 2; ++ks) {
        short8v v;
        #pragma unroll
        for (int e = 0; e < 8; ++e) {
            int k = 16 * ks + 8 * h_ + e;
            float a = (n_ < NNODE && k < NNODE) ? sAdj[n_ * NNODE + k] : 0.f;
            v[e] = (short)bf16b(a);
        }
        adjA[ks] = v;
    }
    // (sW/sAdj/sBias are never overwritten -> no second barrier needed)

    for (;;) {
        // strip must hold graph g: DMA retire (oldest outstanding VMEM)
        asm volatile("s_waitcnt vmcnt(0)" ::: "memory");
        __builtin_amdgcn_sched_barrier(0);

        // swizzled b128 reads (2-3-way banks) -> 32 floats/lane
        f32x4 f0 = *(const f32x4*)(sb + rd0), f1 = *(const f32x4*)(sb + rd1);
        f32x4 f2 = *(const f32x4*)(sb + rd2), f3 = *(const f32x4*)(sb + rd3);
        f32x4 f4 = *(const f32x4*)(sb + rd4), f5 = *(const f32x4*)(sb + rd5);
        f32x4 f6 = *(const f32x4*)(sb + rd6), f7 = *(const f32x4*)(sb + rd7);
        asm volatile("s_waitcnt lgkmcnt(0)" ::: "memory");   // reads landed in regs
        __builtin_amdgcn_sched_barrier(0);

        // strip free -> issue next graph's DMA (in flight across all compute below)
        const int gn = g + TOTW;
        if (gn < NGRAPH) {
            const char* gb = (const char*)x + (size_t)gn * GBYTES;
            #pragma unroll
            for (int j = 0; j < 4; ++j) dma16(gb + srcB[j], sb + j * 1024);
            if (l < 16) dma16(gb + srcB[4], sb + 4096);
        }

        // x A-frags: A[m=rr][k=16ks+8h_+e]
        short8v a0 = mk8(cvtpk(f0.x,f0.y), cvtpk(f0.z,f0.w), cvtpk(f1.x,f1.y), cvtpk(f1.z,f1.w));
        short8v a1 = mk8(cvtpk(f2.x,f2.y), cvtpk(f2.z,f2.w), cvtpk(f3.x,f3.y), cvtpk(f3.z,f3.w));
        short8v a2 = mk8(cvtpk(f4.x,f4.y), cvtpk(f4.z,f4.w), cvtpk(f5.x,f5.y), cvtpk(f5.z,f5.w));
        short8v a3 = mk8(cvtpk(f6.x,f6.y), cvtpk(f6.z,f6.w), cvtpk(f7.x,f7.y), cvtpk(f7.z,f7.w));

        float* og = out + (size_t)g * (NNODE * FDIM);
        #pragma unroll
        for (int hf = 0; hf < 2; ++hf) {     // sequential halves: acc live = 32 regs
            const float bb = hf ? bias1 : bias0;
            f32x16 s, h;
            #pragma unroll
            for (int r2 = 0; r2 < 16; ++r2) { s[r2] = bb; h[r2] = 0.f; }
            s = __builtin_amdgcn_mfma_f32_32x32x16_bf16(a0, wS[hf][0], s, 0, 0, 0);
            h = __builtin_amdgcn_mfma_f32_32x32x16_bf16(a0, wN[hf][0], h, 0, 0, 0);
            s = __builtin_amdgcn_mfma_f32_32x32x16_bf16(a1, wS[hf][1], s, 0, 0, 0);
            h = __builtin_amdgcn_mfma_f32_32x32x16_bf16(a1, wN[hf][1], h, 0, 0, 0);
            s = __builtin_amdgcn_mfma_f32_32x32x16_bf16(a2, wS[hf][2], s, 0, 0, 0);
            h = __builtin_amdgcn_mfma_f32_32x32x16_bf16(a2, wN[hf][2], h, 0, 0, 0);
            s = __builtin_amdgcn_mfma_f32_32x32x16_bf16(a3, wS[hf][3], s, 0, 0, 0);
            h = __builtin_amdgcn_mfma_f32_32x32x16_bf16(a3, wN[hf][3], h, 0, 0, 0);

            // out += adj@h : h (D-layout) -> B-frag via cvt_pk + permlane32_swap
            // (mapping hardware-verified in R10/R11)
#if __has_builtin(__builtin_amdgcn_permlane32_swap)
            #pragma unroll
            for (int ks2 = 0; ks2 < 2; ++ks2) {
                const int rb = 8 * ks2;
                uint32_t A01 = cvtpk(h[rb + 0], h[rb + 1]);
                uint32_t C23 = cvtpk(h[rb + 2], h[rb + 3]);
                uint32_t B45 = cvtpk(h[rb + 4], h[rb + 5]);
                uint32_t D67 = cvtpk(h[rb + 6], h[rb + 7]);
                uint2v rA = __builtin_amdgcn_permlane32_swap(A01, B45, false, false);
                uint2v rC = __builtin_amdgcn_permlane32_swap(C23, D67, false, false);
                s = __builtin_amdgcn_mfma_f32_32x32x16_bf16(
                        adjA[ks2], mk8(rA[0], rC[0], rA[1], rC[1]), s, 0, 0, 0);
            }
#else
            #pragma unroll
            for (int ks2 = 0; ks2 < 2; ++ks2) {
                const int rb = 8 * ks2;
                float o0_ = __shfl_xor(h_ ? h[rb + 0] : h[rb + 4], 32);
                float o1_ = __shfl_xor(h_ ? h[rb + 1] : h[rb + 5], 32);
                float o2_ = __shfl_xor(h_ ? h[rb + 2] : h[rb + 6], 32);
                float o3_ = __shfl_xor(h_ ? h[rb + 3] : h[rb + 7], 32);
                uint32_t l01 = cvtpk(h[rb + 0], h[rb + 1]);
                uint32_t l23 = cvtpk(h[rb + 2], h[rb + 3]);
                uint32_t l45 = cvtpk(h[rb + 4], h[rb + 5]);
                uint32_t l67 = cvtpk(h[rb + 6], h[rb + 7]);
                uint32_t o01 = cvtpk(o0_, o1_);
                uint32_t o23 = cvtpk(o2_, o3_);
                uint32_t w0 = h_ ? o01 : l01;
                uint32_t w1 = h_ ? o23 : l23;
                uint32_t w2 = h_ ? l45 : o01;
                uint32_t w3 = h_ ? l67 : o23;
                s = __builtin_amdgcn_mfma_f32_32x32x16_bf16(
                        adjA[ks2], mk8(w0, w1, w2, w3), s, 0, 0, 0);
            }
#endif
            // store: D[row=(r2&3)+8*(r2>>2)+4h_][col n_]; regs 0..8 cover rows < 17
            #pragma unroll
            for (int r2 = 0; r2 < 9; ++r2) {
                int row = (r2 & 3) + 8 * (r2 >> 2) + 4 * h_;
                if (row < NNODE) og[row * 64 + 32 * hf + n_] = s[r2];
            }
        }

        g = gn;
        if (g >= NGRAPH) break;
    }
}

extern "C" void kernel_launch(void* const* d_in, const int* in_sizes, int n_in,
                              void* d_out, int out_size, void* d_ws, size_t ws_size,
                              hipStream_t stream) {
    (void)in_sizes; (void)n_in; (void)d_ws; (void)ws_size; (void)out_size;
    const float* x      = (const float*)d_in[0];
    const float* adj    = (const float*)d_in[1];
    const float* wself  = (const float*)d_in[2];
    const float* wneigh = (const float*)d_in[3];
    const float* bias   = (const float*)d_in[4];
    float* out = (float*)d_out;
    egc_kernel<<<NBLOCK, 256, 0, stream>>>(x, adj, wself, wneigh, bias, out);
}

// Round 13
// 165.550 us; speedup vs baseline: 1.3431x; 1.3431x over previous
//
#include <hip/hip_runtime.h>
#include <hip/hip_bf16.h>
#include <stdint.h>

#define NNODE  17
#define FDIM   64
#define NBLOCK 512
#define GPW    32               // 512 blk x 4 waves x 32 = 65536 graphs; 1 resident round
#define WSTR   136              // W2T row stride in u16 (272B, 16B-aligned)
#define GB     4352             // bytes per graph (17*64*4)

typedef __attribute__((ext_vector_type(8)))  short short8v;
typedef __attribute__((ext_vector_type(4)))  float f32x4;
typedef __attribute__((ext_vector_type(16))) float f32x16;
typedef __attribute__((ext_vector_type(2)))  unsigned int uint2v;

__device__ __forceinline__ uint32_t bf16b(float f) {
    uint32_t u = __float_as_uint(f);
    return (u + 0x7fffu + ((u >> 16) & 1u)) >> 16;   // RNE (prologue only)
}
__device__ __forceinline__ uint32_t cvtpk(float lo, float hi) {   // v_cvt_pk_bf16_f32
    __hip_bfloat162 b = __float22bfloat162_rn(make_float2(lo, hi));
    return *reinterpret_cast<uint32_t*>(&b);
}
__device__ __forceinline__ short8v mk8(uint32_t w0, uint32_t w1, uint32_t w2, uint32_t w3) {
    union { uint32_t u[4]; short8v v; } c;
    c.u[0] = w0; c.u[1] = w1; c.u[2] = w2; c.u[3] = w3;
    return c.v;
}

// Zero LDS in the steady-state loop: A-fragments load straight from global
// (8 x dwordx4 per graph, one base + imm offsets; every 128B line fully
// consumed by the same wave's burst -> L1/L2-friendly). Barrier-free loop,
// double-buffered regs, contiguous per-wave streams.
__global__ __launch_bounds__(256, 2) void egc_kernel(
    const float* __restrict__ x, const float* __restrict__ adj,
    const float* __restrict__ wself, const float* __restrict__ wneigh,
    const float* __restrict__ bias, float* __restrict__ out)
{
    __shared__ __align__(16) uint16_t sW[64 * WSTR];   // prologue-only
    __shared__ float sAdj[NNODE * NNODE];
    __shared__ float sBias[FDIM];

    const int t  = threadIdx.x;
    const int l  = t & 63;
    const int wv = t >> 6;
    const int n_ = l & 31;            // A.m / B.n / D.col
    const int h_ = l >> 5;            // k-half / D-row +4
    const int rr = (n_ < 16) ? n_ : 16;   // clamped x-row (lanes 17..31 dup row 16: finite, masked)

    // ---- prologue: W2T[o][k] (k<64: Ws[k][o] else Wn[k-64][o]), adj, bias ----
    for (int idx = t; idx < FDIM * 128; idx += 256) {
        int o = idx >> 7, k = idx & 127;
        float v = (k < 64) ? wself[k * 64 + o] : wneigh[(k - 64) * 64 + o];
        sW[o * WSTR + k] = (uint16_t)bf16b(v);
    }
    for (int i = t; i < NNODE * NNODE; i += 256) sAdj[i] = adj[i];
    if (t < FDIM) sBias[t] = bias[t];
    __syncthreads();

    // W B-frags: B[k=16ks+8h_+e][n=32hf+n_]
    short8v wS[2][4], wN[2][4];
    #pragma unroll
    for (int hf = 0; hf < 2; ++hf)
        #pragma unroll
        for (int ks = 0; ks < 4; ++ks) {
            wS[hf][ks] = *(const short8v*)&sW[(32*hf + n_) * WSTR + 16*ks + 8*h_];
            wN[hf][ks] = *(const short8v*)&sW[(32*hf + n_) * WSTR + 64 + 16*ks + 8*h_];
        }
    const float bias0 = sBias[n_], bias1 = sBias[32 + n_];

    // adj A-frags: A[m=n_][k=16ks2+8h_+e] = adj[n_][k], explicit zero pad (no NaN)
    short8v adjA[2];
    #pragma unroll
    for (int ks = 0; ks < 2; ++ks) {
        short8v v;
        #pragma unroll
        for (int e = 0; e < 8; ++e) {
            int k = 16 * ks + 8 * h_ + e;
            float a = (n_ < NNODE && k < NNODE) ? sAdj[n_ * NNODE + k] : 0.f;
            v[e] = (short)bf16b(a);
        }
        adjA[ks] = v;
    }
    // ---- no __syncthreads / no LDS access below this line ----

    const size_t g0 = ((size_t)blockIdx.x * 4 + wv) * GPW;
    const char* gl = (const char*)x + g0 * GB + rr * 256 + h_ * 32;
    float*      og = out + g0 * (size_t)(NNODE * FDIM);

    f32x4 fA[8], fB[8];

    // 8 loads, single base + immediate offsets; lanes cover rows 0..16 x both halves
    #define LOADG(F, P) {                                                          \
        F[0] = *(const f32x4*)((P) + 0);   F[1] = *(const f32x4*)((P) + 16);       \
        F[2] = *(const f32x4*)((P) + 64);  F[3] = *(const f32x4*)((P) + 80);       \
        F[4] = *(const f32x4*)((P) + 128); F[5] = *(const f32x4*)((P) + 144);      \
        F[6] = *(const f32x4*)((P) + 192); F[7] = *(const f32x4*)((P) + 208); }

#if __has_builtin(__builtin_amdgcn_permlane32_swap)
    #define HTRANS(sv, hv, ks2)                                                    \
        {                                                                          \
            const int rb = 8 * (ks2);                                              \
            uint32_t A01 = cvtpk(hv[rb + 0], hv[rb + 1]);                          \
            uint32_t C23 = cvtpk(hv[rb + 2], hv[rb + 3]);                          \
            uint32_t B45 = cvtpk(hv[rb + 4], hv[rb + 5]);                          \
            uint32_t D67 = cvtpk(hv[rb + 6], hv[rb + 7]);                          \
            uint2v rA = __builtin_amdgcn_permlane32_swap(A01, B45, false, false);  \
            uint2v rC = __builtin_amdgcn_permlane32_swap(C23, D67, false, false);  \
            sv = __builtin_amdgcn_mfma_f32_32x32x16_bf16(                          \
                     adjA[ks2], mk8(rA[0], rC[0], rA[1], rC[1]), sv, 0, 0, 0);     \
        }
#else
    #define HTRANS(sv, hv, ks2)                                                    \
        {                                                                          \
            const int rb = 8 * (ks2);                                              \
            float o0_ = __shfl_xor(h_ ? hv[rb + 0] : hv[rb + 4], 32);              \
            float o1_ = __shfl_xor(h_ ? hv[rb + 1] : hv[rb + 5], 32);              \
            float o2_ = __shfl_xor(h_ ? hv[rb + 2] : hv[rb + 6], 32);              \
            float o3_ = __shfl_xor(h_ ? hv[rb + 3] : hv[rb + 7], 32);              \
            uint32_t l01 = cvtpk(hv[rb + 0], hv[rb + 1]);                          \
            uint32_t l23 = cvtpk(hv[rb + 2], hv[rb + 3]);                          \
            uint32_t l45 = cvtpk(hv[rb + 4], hv[rb + 5]);                          \
            uint32_t l67 = cvtpk(hv[rb + 6], hv[rb + 7]);                          \
            uint32_t o01 = cvtpk(o0_, o1_);                                        \
            uint32_t o23 = cvtpk(o2_, o3_);                                        \
            uint32_t w0 = h_ ? o01 : l01;                                          \
            uint32_t w1 = h_ ? o23 : l23;                                          \
            uint32_t w2 = h_ ? l45 : o01;                                          \
            uint32_t w3 = h_ ? l67 : o23;                                          \
            sv = __builtin_amdgcn_mfma_f32_32x32x16_bf16(                          \
                     adjA[ks2], mk8(w0, w1, w2, w3), sv, 0, 0, 0);                 \
        }
#endif

    #define COMPUTE(F, OG) {                                                       \
        short8v a0 = mk8(cvtpk(F[0].x,F[0].y), cvtpk(F[0].z,F[0].w),               \
                         cvtpk(F[1].x,F[1].y), cvtpk(F[1].z,F[1].w));              \
        short8v a1 = mk8(cvtpk(F[2].x,F[2].y), cvtpk(F[2].z,F[2].w),               \
                         cvtpk(F[3].x,F[3].y), cvtpk(F[3].z,F[3].w));              \
        short8v a2 = mk8(cvtpk(F[4].x,F[4].y), cvtpk(F[4].z,F[4].w),               \
                         cvtpk(F[5].x,F[5].y), cvtpk(F[5].z,F[5].w));              \
        short8v a3 = mk8(cvtpk(F[6].x,F[6].y), cvtpk(F[6].z,F[6].w),               \
                         cvtpk(F[7].x,F[7].y), cvtpk(F[7].z,F[7].w));              \
        _Pragma("unroll")                                                          \
        for (int hf = 0; hf < 2; ++hf) {                                           \
            const float bb = hf ? bias1 : bias0;                                   \
            f32x16 s, h;                                                           \
            _Pragma("unroll")                                                      \
            for (int r2 = 0; r2 < 16; ++r2) { s[r2] = bb; h[r2] = 0.f; }           \
            s = __builtin_amdgcn_mfma_f32_32x32x16_bf16(a0, wS[hf][0], s, 0,0,0);  \
            h = __builtin_amdgcn_mfma_f32_32x32x16_bf16(a0, wN[hf][0], h, 0,0,0);  \
            s = __builtin_amdgcn_mfma_f32_32x32x16_bf16(a1, wS[hf][1], s, 0,0,0);  \
            h = __builtin_amdgcn_mfma_f32_32x32x16_bf16(a1, wN[hf][1], h, 0,0,0);  \
            s = __builtin_amdgcn_mfma_f32_32x32x16_bf16(a2, wS[hf][2], s, 0,0,0);  \
            h = __builtin_amdgcn_mfma_f32_32x32x16_bf16(a2, wN[hf][2], h, 0,0,0);  \
            s = __builtin_amdgcn_mfma_f32_32x32x16_bf16(a3, wS[hf][3], s, 0,0,0);  \
            h = __builtin_amdgcn_mfma_f32_32x32x16_bf16(a3, wN[hf][3], h, 0,0,0);  \
            HTRANS(s, h, 0)                                                        \
            HTRANS(s, h, 1)                                                        \
            _Pragma("unroll")                                                      \
            for (int r2 = 0; r2 < 9; ++r2) {                                       \
                int row = (r2 & 3) + 8 * (r2 >> 2) + 4 * h_;                       \
                if (row < NNODE) (OG)[row * 64 + 32 * hf + n_] = s[r2];            \
            }                                                                      \
        }                                                                          \
    }

    LOADG(fA, gl);
    #pragma unroll 1
    for (int gi = 0; gi < GPW; gi += 2) {
        LOADG(fB, gl + GB);                       // prefetch graph gi+1
        COMPUTE(fA, og);                          // compute graph gi
        if (gi + 2 < GPW) LOADG(fA, gl + 2 * GB); // prefetch graph gi+2
        COMPUTE(fB, og + NNODE * FDIM);           // compute graph gi+1
        gl += 2 * GB;
        og += 2 * (NNODE * FDIM);
    }

    #undef LOADG
    #undef HTRANS
    #undef COMPUTE
}

extern "C" void kernel_launch(void* const* d_in, const int* in_sizes, int n_in,
                              void* d_out, int out_size, void* d_ws, size_t ws_size,
                              hipStream_t stream) {
    (void)in_sizes; (void)n_in; (void)d_ws; (void)ws_size; (void)out_size;
    const float* x      = (const float*)d_in[0];
    const float* adj    = (const float*)d_in[1];
    const float* wself  = (const float*)d_in[2];
    const float* wneigh = (const float*)d_in[3];
    const float* bias   = (const float*)d_in[4];
    float* out = (float*)d_out;
    egc_kernel<<<NBLOCK, 256, 0, stream>>>(x, adj, wself, wneigh, bias, out);
}